// Round 1
// baseline (715.999 us; speedup 1.0000x reference)
//
#include <hip/hip_runtime.h>
#include <hip/hip_bf16.h>

typedef __attribute__((ext_vector_type(8))) short bf16x8;
typedef __attribute__((ext_vector_type(4))) float f32x4;

#define HID 64
#define TSTEPS 256
#define BATCH 4096
#define BT 16

__device__ __forceinline__ float frcp(float x){ return __builtin_amdgcn_rcpf(x); }
__device__ __forceinline__ float sigm(float x){ return frcp(1.f + __expf(-x)); }
__device__ __forceinline__ float tanh_(float x){ return 1.f - 2.f*frcp(1.f + __expf(2.f*x)); }

__device__ __forceinline__ ushort f2bf(float f){
  unsigned u = __float_as_uint(f);
  u += 0x7fff + ((u>>16)&1);
  return (ushort)(u>>16);
}
__device__ __forceinline__ float bf2f(ushort u){ return __uint_as_float(((unsigned)u)<<16); }

// XOR-swizzled LDS byte address: row-major [16][128] bf16 (256B rows),
// byte ^= (row&7)<<4 keeps 16B alignment, kills the 16-way bank conflict.
__device__ __forceinline__ int swz(int row, int b){ return row*256 + (b ^ ((row&7)<<4)); }

template<int KSTEPS, bool FIRST, bool LAST>
__device__ __forceinline__ void run_layer(char* actb,
    const float* __restrict__ Wih, const float* __restrict__ Whh,
    const float* __restrict__ bih, const float* __restrict__ bhh,
    const float* __restrict__ x, ushort* __restrict__ hbuf,
    int row0, int tid){
  const int IN   = KSTEPS*32 - 64;   // 32 (layer0) or 64
  const int lane = tid & 63;
  const int wid  = tid >> 6;         // 0..3
  const int l15  = lane & 15;
  const int lhi  = lane >> 4;        // 0..3

  // ---- stationary weights as B-fragments in registers + bias ----
  bf16x8 wf[KSTEPS][4];
  float biasv[4];
  #pragma unroll
  for (int g = 0; g < 4; ++g){
    int n = g*64 + wid*16 + l15;     // gate column (B col = lane&15)
    biasv[g] = bih[n] + bhh[n];
    #pragma unroll
    for (int kt = 0; kt < KSTEPS; ++kt){
      int kb = kt*32 + lhi*8;        // same kappa(lane,j) as A-frag reads
      const float* src = (kb < IN) ? (Wih + (size_t)n*IN + kb)
                                   : (Whh + (size_t)n*64 + (kb - IN));
      bf16x8 v;
      #pragma unroll
      for (int j = 0; j < 8; ++j) v[j] = (short)f2bf(src[j]);
      wf[kt][g] = v;
    }
  }

  // ---- zero act tile (h0 = 0) ----
  *reinterpret_cast<int4*>(actb + tid*16) = make_int4(0,0,0,0);
  __syncthreads();

  float cst[4] = {0.f, 0.f, 0.f, 0.f};

  for (int t = 0; t < TSTEPS; ++t){
    // ---- stage x_t into LDS cols [0,IN) ----
    if (FIRST){
      int row = tid >> 4;
      int c2  = (tid & 15)*2;
      const float* xp = x + ((size_t)(row0+row)*TSTEPS + t)*32 + c2;
      float a0 = xp[0], a1 = xp[1];
      unsigned pk = (unsigned)f2bf(a0) | ((unsigned)f2bf(a1) << 16);
      *reinterpret_cast<unsigned*>(actb + swz(row, c2*2)) = pk;
    } else {
      int row = tid >> 4;
      int c4  = (tid & 15)*4;
      const ushort* hp = hbuf + (size_t)t*BATCH*HID + (size_t)(row0+row)*HID + c4;
      uint2 v = *reinterpret_cast<const uint2*>(hp);
      *reinterpret_cast<uint2*>(actb + swz(row, c4*2)) = v;
    }
    __syncthreads();

    // ---- gates = bias + [x;h] @ Wcat^T ----
    f32x4 acc[4];
    #pragma unroll
    for (int g = 0; g < 4; ++g){
      acc[g][0] = biasv[g]; acc[g][1] = biasv[g];
      acc[g][2] = biasv[g]; acc[g][3] = biasv[g];
    }
    #pragma unroll
    for (int kt = 0; kt < KSTEPS; ++kt){
      bf16x8 a = *reinterpret_cast<const bf16x8*>(actb + swz(l15, (kt*32 + lhi*8)*2));
      #pragma unroll
      for (int g = 0; g < 4; ++g)
        acc[g] = __builtin_amdgcn_mfma_f32_16x16x32_bf16(a, wf[kt][g], acc[g], 0, 0, 0);
    }

    // ---- elementwise: lane-local (col=lane&15, row=lhi*4+r) ----
    ushort hres[4];
    #pragma unroll
    for (int r = 0; r < 4; ++r){
      float iv = sigm(acc[0][r]);
      float fv = sigm(acc[1][r]);
      float gv = tanh_(acc[2][r]);
      float ov = sigm(acc[3][r]);
      cst[r] = fv*cst[r] + iv*gv;
      hres[r] = f2bf(ov * tanh_(cst[r]));
    }
    __syncthreads();   // all A-frag reads done before overwriting h region

    int ch = wid*16 + l15;           // hidden unit
    #pragma unroll
    for (int r = 0; r < 4; ++r){
      int row = lhi*4 + r;
      *reinterpret_cast<ushort*>(actb + swz(row, (IN + ch)*2)) = hres[r];
      if (!LAST || t == TSTEPS-1){
        hbuf[(size_t)t*BATCH*HID + (size_t)(row0+row)*HID + ch] = hres[r];
      }
    }
  }
  __syncthreads();
}

__global__ __launch_bounds__(256, 1) void lstm3_kernel(
    const float* __restrict__ x,
    const float* Wih0, const float* Whh0, const float* bih0, const float* bhh0,
    const float* Wih1, const float* Whh1, const float* bih1, const float* bhh1,
    const float* Wih2, const float* Whh2, const float* bih2, const float* bhh2,
    ushort* __restrict__ hbuf){
  __shared__ char actb[BT*256];
  int tid  = threadIdx.x;
  int row0 = blockIdx.x * BT;
  run_layer<3, true,  false>(actb, Wih0, Whh0, bih0, bhh0, x, hbuf, row0, tid);
  run_layer<4, false, false>(actb, Wih1, Whh1, bih1, bhh1, x, hbuf, row0, tid);
  run_layer<4, false, true >(actb, Wih2, Whh2, bih2, bhh2, x, hbuf, row0, tid);
}

__global__ void fc_kernel(const ushort* __restrict__ hlast,
                          const float* __restrict__ w1, const float* __restrict__ b1,
                          const float* __restrict__ w2, const float* __restrict__ b2,
                          float* __restrict__ out){
  int b = blockIdx.x*256 + threadIdx.x;
  float h[HID];
  const ushort* hp = hlast + (size_t)b*HID;
  #pragma unroll
  for (int i = 0; i < HID; ++i) h[i] = bf2f(hp[i]);
  float acc = b2[0];
  #pragma unroll
  for (int j = 0; j < 32; ++j){
    float z = b1[j];
    #pragma unroll
    for (int i = 0; i < HID; ++i) z += h[i]*w1[j*HID + i];
    z = fmaxf(z, 0.f);
    acc += z * w2[j];
  }
  out[b] = acc;
}

extern "C" void kernel_launch(void* const* d_in, const int* in_sizes, int n_in,
                              void* d_out, int out_size, void* d_ws, size_t ws_size,
                              hipStream_t stream){
  const float* x     = (const float*)d_in[0];
  const float* Wih0  = (const float*)d_in[1];
  const float* Whh0  = (const float*)d_in[2];
  const float* bih0  = (const float*)d_in[3];
  const float* bhh0  = (const float*)d_in[4];
  const float* Wih1  = (const float*)d_in[5];
  const float* Whh1  = (const float*)d_in[6];
  const float* bih1  = (const float*)d_in[7];
  const float* bhh1  = (const float*)d_in[8];
  const float* Wih2  = (const float*)d_in[9];
  const float* Whh2  = (const float*)d_in[10];
  const float* bih2  = (const float*)d_in[11];
  const float* bhh2  = (const float*)d_in[12];
  const float* fc1w  = (const float*)d_in[13];
  const float* fc1b  = (const float*)d_in[14];
  const float* fc2w  = (const float*)d_in[15];
  const float* fc2b  = (const float*)d_in[16];

  ushort* hbuf = (ushort*)d_ws;   // [T, B, 64] bf16 = 128 MiB, ping-ponged in place

  lstm3_kernel<<<BATCH/BT, 256, 0, stream>>>(x,
      Wih0, Whh0, bih0, bhh0,
      Wih1, Whh1, bih1, bhh1,
      Wih2, Whh2, bih2, bhh2, hbuf);

  fc_kernel<<<BATCH/256, 256, 0, stream>>>(
      hbuf + (size_t)(TSTEPS-1)*BATCH*HID, fc1w, fc1b, fc2w, fc2b, (float*)d_out);
}

// Round 2
// 437.322 us; speedup vs baseline: 1.6372x; 1.6372x over previous
//
#include <hip/hip_runtime.h>
#include <hip/hip_bf16.h>

typedef __attribute__((ext_vector_type(8))) short bf16x8;
typedef __attribute__((ext_vector_type(4))) float f32x4;

#define HID 64
#define TSTEPS 256
#define BATCH 4096
#define BT 16

__device__ __forceinline__ float frcp(float x){ return __builtin_amdgcn_rcpf(x); }
__device__ __forceinline__ float sigm(float x){ return frcp(1.f + __expf(-x)); }
__device__ __forceinline__ float tanh_(float x){ return 1.f - 2.f*frcp(1.f + __expf(2.f*x)); }

__device__ __forceinline__ ushort f2bf(float f){
  unsigned u = __float_as_uint(f);
  u += 0x7fff + ((u>>16)&1);
  return (ushort)(u>>16);
}
__device__ __forceinline__ float bf2f(ushort u){ return __uint_as_float(((unsigned)u)<<16); }

// XOR-swizzled LDS byte address: row-major [16][128] bf16 (256B rows),
// byte ^= (row&7)<<4 keeps 16B alignment, kills bank conflicts on ds_read_b128.
__device__ __forceinline__ int swz(int row, int b){ return row*256 + (b ^ ((row&7)<<4)); }

template<int KS>
__device__ __forceinline__ void load_wb(const float* __restrict__ Wih,
    const float* __restrict__ Whh, const float* __restrict__ bih,
    const float* __restrict__ bhh, bf16x8 (&wf)[KS][4], float (&bv)[4],
    int wid, int l15, int lhi){
  const int IN = KS*32 - 64;   // 32 (layer0) or 64
  #pragma unroll
  for (int g = 0; g < 4; ++g){
    int n = g*64 + wid*16 + l15;           // gate column (B col = lane&15)
    bv[g] = bih[n] + bhh[n];
    #pragma unroll
    for (int kt = 0; kt < KS; ++kt){
      int kb = kt*32 + lhi*8;              // same kappa(lane,j) as A-frag reads
      const float* src = (kb < IN) ? (Wih + (size_t)n*IN + kb)
                                   : (Whh + (size_t)n*64 + (kb - IN));
      bf16x8 v;
      #pragma unroll
      for (int j = 0; j < 8; ++j) v[j] = (short)f2bf(src[j]);
      wf[kt][g] = v;
    }
  }
}

template<int KS>
__device__ __forceinline__ void layer_step(const char* act, const bf16x8 (&wf)[KS][4],
    const float (&bv)[4], float (&cst)[4], ushort (&hres)[4], int l15, int lhi){
  f32x4 acc[4];
  #pragma unroll
  for (int g = 0; g < 4; ++g){
    acc[g][0] = bv[g]; acc[g][1] = bv[g]; acc[g][2] = bv[g]; acc[g][3] = bv[g];
  }
  #pragma unroll
  for (int kt = 0; kt < KS; ++kt){
    bf16x8 a = *reinterpret_cast<const bf16x8*>(act + swz(l15, (kt*32 + lhi*8)*2));
    #pragma unroll
    for (int g = 0; g < 4; ++g)
      acc[g] = __builtin_amdgcn_mfma_f32_16x16x32_bf16(a, wf[kt][g], acc[g], 0, 0, 0);
  }
  // elementwise: lane-local (col=lane&15, row=lhi*4+r)
  #pragma unroll
  for (int r = 0; r < 4; ++r){
    float iv = sigm(acc[0][r]);
    float fv = sigm(acc[1][r]);
    float gv = tanh_(acc[2][r]);
    float ov = sigm(acc[3][r]);
    cst[r] = fv*cst[r] + iv*gv;
    hres[r] = f2bf(ov * tanh_(cst[r]));
  }
}

__device__ __forceinline__ void write_h(char* act, int colbase,
    const ushort (&hres)[4], int wid, int l15, int lhi){
  int ch = colbase + wid*16 + l15;
  #pragma unroll
  for (int r = 0; r < 4; ++r)
    *reinterpret_cast<ushort*>(act + swz(lhi*4 + r, ch*2)) = hres[r];
}

__global__ __launch_bounds__(256, 1) void lstm3_fused_kernel(
    const float* __restrict__ x,
    const float* Wih0, const float* Whh0, const float* bih0, const float* bhh0,
    const float* Wih1, const float* Whh1, const float* bih1, const float* bhh1,
    const float* Wih2, const float* Whh2, const float* bih2, const float* bhh2,
    const float* __restrict__ fc1w, const float* __restrict__ fc1b,
    const float* __restrict__ fc2w, const float* __restrict__ fc2b,
    float* __restrict__ out){
  // act0: [16][96]  cols 0-31: x_t,     cols 32-95:  h0_{t-1}   (256B row stride)
  // act1: [16][128] cols 0-63: h0_t,    cols 64-127: h1_{t-1}
  // act2: [16][128] cols 0-63: h1_t,    cols 64-127: h2_{t-1}
  __shared__ char act0[BT*256];
  __shared__ char act1[BT*256];
  __shared__ char act2[BT*256];
  __shared__ float fcbuf[BT*16];

  const int tid  = threadIdx.x;
  const int lane = tid & 63;
  const int wid  = tid >> 6;
  const int l15  = lane & 15;
  const int lhi  = lane >> 4;
  const int row0 = blockIdx.x * BT;

  // ---- stationary weights for all 3 layers in registers ----
  bf16x8 wf0[3][4], wf1[4][4], wf2[4][4];
  float b0v[4], b1v[4], b2v[4];
  load_wb<3>(Wih0, Whh0, bih0, bhh0, wf0, b0v, wid, l15, lhi);
  load_wb<4>(Wih1, Whh1, bih1, bhh1, wf1, b1v, wid, l15, lhi);
  load_wb<4>(Wih2, Whh2, bih2, bhh2, wf2, b2v, wid, l15, lhi);

  // ---- zero act tiles (h0 = c0 = 0) ----
  *reinterpret_cast<int4*>(act0 + tid*16) = make_int4(0,0,0,0);
  *reinterpret_cast<int4*>(act1 + tid*16) = make_int4(0,0,0,0);
  *reinterpret_cast<int4*>(act2 + tid*16) = make_int4(0,0,0,0);

  // ---- x staging: thread covers (row = tid>>4, cols (tid&15)*2 .. +1) ----
  const int xrow = tid >> 4;
  const int xc   = (tid & 15)*2;
  const float* xbase = x + ((size_t)(row0 + xrow)*TSTEPS)*32 + xc;
  {
    float2 v0 = *reinterpret_cast<const float2*>(xbase);        // x(0)
    unsigned pk = (unsigned)f2bf(v0.x) | ((unsigned)f2bf(v0.y) << 16);
    *reinterpret_cast<unsigned*>(act0 + swz(xrow, xc*2)) = pk;
  }
  float2 xr = *reinterpret_cast<const float2*>(xbase + 32);     // x(1) in flight
  __syncthreads();

  float cst0[4] = {0,0,0,0}, cst1[4] = {0,0,0,0}, cst2[4] = {0,0,0,0};
  ushort h0r[4], h1r[4], h2r[4];

  for (int t = 0; t < TSTEPS; ++t){
    layer_step<3>(act0, wf0, b0v, cst0, h0r, l15, lhi);
    __syncthreads();                         // B1: all done reading act0
    write_h(act0, 32, h0r, wid, l15, lhi);   // h0_t for next step
    write_h(act1, 0,  h0r, wid, l15, lhi);   // layer1 input
    {                                        // stage x(t+1), prefetch x(t+2)
      unsigned pk = (unsigned)f2bf(xr.x) | ((unsigned)f2bf(xr.y) << 16);
      *reinterpret_cast<unsigned*>(act0 + swz(xrow, xc*2)) = pk;
      int tn = (t + 2 < TSTEPS) ? t + 2 : TSTEPS - 1;
      xr = *reinterpret_cast<const float2*>(xbase + (size_t)tn*32);
    }
    __syncthreads();                         // B2: act1 ready
    layer_step<4>(act1, wf1, b1v, cst1, h1r, l15, lhi);
    __syncthreads();                         // B3: all done reading act1
    write_h(act1, 64, h1r, wid, l15, lhi);
    write_h(act2, 0,  h1r, wid, l15, lhi);
    __syncthreads();                         // B4: act2 ready
    layer_step<4>(act2, wf2, b2v, cst2, h2r, l15, lhi);
    __syncthreads();                         // B5: all done reading act2 (WAR)
    write_h(act2, 64, h2r, wid, l15, lhi);
  }
  __syncthreads();                           // final h2 visible in act2.hi

  // ---- fused FC head: 256 threads = 16 rows x 16 j-slots (2 j each) ----
  {
    const int row  = tid & 15;
    const int slot = tid >> 4;
    float hv[HID];
    #pragma unroll
    for (int i = 0; i < HID; ++i)
      hv[i] = bf2f(*reinterpret_cast<const ushort*>(act2 + swz(row, (64 + i)*2)));
    float p = 0.f;
    #pragma unroll
    for (int jj = 0; jj < 2; ++jj){
      int j = slot*2 + jj;
      float z = fc1b[j];
      #pragma unroll
      for (int i = 0; i < HID; ++i) z += hv[i]*fc1w[j*HID + i];
      z = fmaxf(z, 0.f);
      p += z * fc2w[j];
    }
    fcbuf[row*16 + slot] = p;
  }
  __syncthreads();
  if (tid < BT){
    float s = fc2b[0];
    #pragma unroll
    for (int k = 0; k < 16; ++k) s += fcbuf[tid*16 + k];
    out[row0 + tid] = s;
  }
}

extern "C" void kernel_launch(void* const* d_in, const int* in_sizes, int n_in,
                              void* d_out, int out_size, void* d_ws, size_t ws_size,
                              hipStream_t stream){
  const float* x    = (const float*)d_in[0];
  const float* Wih0 = (const float*)d_in[1];
  const float* Whh0 = (const float*)d_in[2];
  const float* bih0 = (const float*)d_in[3];
  const float* bhh0 = (const float*)d_in[4];
  const float* Wih1 = (const float*)d_in[5];
  const float* Whh1 = (const float*)d_in[6];
  const float* bih1 = (const float*)d_in[7];
  const float* bhh1 = (const float*)d_in[8];
  const float* Wih2 = (const float*)d_in[9];
  const float* Whh2 = (const float*)d_in[10];
  const float* bih2 = (const float*)d_in[11];
  const float* bhh2 = (const float*)d_in[12];
  const float* fc1w = (const float*)d_in[13];
  const float* fc1b = (const float*)d_in[14];
  const float* fc2w = (const float*)d_in[15];
  const float* fc2b = (const float*)d_in[16];

  lstm3_fused_kernel<<<BATCH/BT, 256, 0, stream>>>(x,
      Wih0, Whh0, bih0, bhh0,
      Wih1, Whh1, bih1, bhh1,
      Wih2, Whh2, bih2, bhh2,
      fc1w, fc1b, fc2w, fc2b, (float*)d_out);
}

// Round 3
// 421.111 us; speedup vs baseline: 1.7003x; 1.0385x over previous
//
#include <hip/hip_runtime.h>
#include <hip/hip_bf16.h>

typedef __attribute__((ext_vector_type(8))) short bf16x8;
typedef __attribute__((ext_vector_type(4))) float f32x4;

#define HID 64
#define TSTEPS 256
#define BATCH 4096
#define BT 16
#define RSTRIDE 512   // bytes per LDS tile row

__device__ __forceinline__ float frcp(float x){ return __builtin_amdgcn_rcpf(x); }

__device__ __forceinline__ ushort f2bf(float f){
  unsigned u = __float_as_uint(f);
  u += 0x7fff + ((u>>16)&1);
  return (ushort)(u>>16);
}
__device__ __forceinline__ float bf2f(ushort u){ return __uint_as_float(((unsigned)u)<<16); }

// XOR-swizzled LDS byte address within a [16][RSTRIDE] byte tile.
__device__ __forceinline__ int swz(int row, int b){ return row*RSTRIDE + (b ^ ((row&7)<<4)); }

// Stationary weight B-fragments (gate g, k-tile kt) + combined bias.
template<int KS>
__device__ __forceinline__ void load_wb(const float* __restrict__ Wih,
    const float* __restrict__ Whh, const float* __restrict__ bih,
    const float* __restrict__ bhh, bf16x8 (&wf)[KS][4], float (&bv)[4],
    int wid, int l15, int lhi){
  const int IN = KS*32 - 64;   // 32 (layer0) or 64
  #pragma unroll
  for (int g = 0; g < 4; ++g){
    int n = g*64 + wid*16 + l15;           // gate column (B col = lane&15)
    bv[g] = bih[n] + bhh[n];
    #pragma unroll
    for (int kt = 0; kt < KS; ++kt){
      int kb = kt*32 + lhi*8;              // same kappa(lane,j) as A-frag reads
      const float* src = (kb < IN) ? (Wih + (size_t)n*IN + kb)
                                   : (Whh + (size_t)n*64 + (kb - IN));
      bf16x8 v;
      #pragma unroll
      for (int j = 0; j < 8; ++j) v[j] = (short)f2bf(src[j]);
      wf[kt][g] = v;
    }
  }
}

__device__ __forceinline__ void acc_init(f32x4 (&acc)[4], const float (&bv)[4]){
  #pragma unroll
  for (int g = 0; g < 4; ++g){
    acc[g][0] = bv[g]; acc[g][1] = bv[g]; acc[g][2] = bv[g]; acc[g][3] = bv[g];
  }
}

// One k-tile (K=32) of all 4 gates from LDS cols [colbase, colbase+32).
__device__ __forceinline__ void mfma_kt(const char* act, int colbase,
    const bf16x8 (&wfk)[4], f32x4 (&acc)[4], int l15, int lhi){
  bf16x8 a = *reinterpret_cast<const bf16x8*>(act + swz(l15, (colbase + lhi*8)*2));
  #pragma unroll
  for (int g = 0; g < 4; ++g)
    acc[g] = __builtin_amdgcn_mfma_f32_16x16x32_bf16(a, wfk[g], acc[g], 0, 0, 0);
}

// Merged-denominator LSTM cell update: 5 exp + 2 rcp per cell.
__device__ __forceinline__ void ew(const f32x4 (&acc)[4], float (&cst)[4],
                                   ushort (&hres)[4]){
  #pragma unroll
  for (int r = 0; r < 4; ++r){
    float Ai = __expf(-acc[0][r]);        // e^{-i}
    float Bf = __expf(-acc[1][r]);        // e^{-f}
    float G  = __expf(2.f*acc[2][r]);     // e^{2g}
    float O  = __expf(-acc[3][r]);        // e^{-o}
    float a1 = 1.f + Ai, b1 = 1.f + Bf, gp = G + 1.f, gm = G - 1.f;
    float cp = (cst[r]*a1*gp + b1*gm) * frcp(a1*b1*gp);
    cst[r] = cp;
    float C2 = __expf(2.f*cp);            // e^{2c'}
    hres[r] = f2bf((C2 - 1.f) * frcp((1.f + O)*(C2 + 1.f)));
  }
}

__device__ __forceinline__ void write_h(char* act, int colbase,
    const ushort (&hres)[4], int wid, int l15, int lhi){
  int ch = colbase + wid*16 + l15;
  #pragma unroll
  for (int r = 0; r < 4; ++r)
    *reinterpret_cast<ushort*>(act + swz(lhi*4 + r, ch*2)) = hres[r];
}

// LDS column maps (bf16 cols, row stride RSTRIDE bytes):
// act0: [ 0.. 31] x slot0 | [32.. 63] x slot1 | [64..127] h0 slot0 | [128..191] h0 slot1
// act1: [ 0.. 63] h0_t    | [64..127] h1 slot0 | [128..191] h1 slot1
// act2: [ 0.. 63] h1_t    | [64..127] h2 slot0 | [128..191] h2 slot1
__global__ __launch_bounds__(256, 1) void lstm3_fused_kernel(
    const float* __restrict__ x,
    const float* Wih0, const float* Whh0, const float* bih0, const float* bhh0,
    const float* Wih1, const float* Whh1, const float* bih1, const float* bhh1,
    const float* Wih2, const float* Whh2, const float* bih2, const float* bhh2,
    const float* __restrict__ fc1w, const float* __restrict__ fc1b,
    const float* __restrict__ fc2w, const float* __restrict__ fc2b,
    float* __restrict__ out){
  __shared__ char act0[BT*RSTRIDE];
  __shared__ char act1[BT*RSTRIDE];
  __shared__ char act2[BT*RSTRIDE];
  __shared__ float fcbuf[BT*16];

  const int tid  = threadIdx.x;
  const int lane = tid & 63;
  const int wid  = tid >> 6;
  const int l15  = lane & 15;
  const int lhi  = lane >> 4;
  const int row0 = blockIdx.x * BT;

  bf16x8 wf0[3][4], wf1[4][4], wf2[4][4];
  float b0v[4], b1v[4], b2v[4];
  load_wb<3>(Wih0, Whh0, bih0, bhh0, wf0, b0v, wid, l15, lhi);
  load_wb<4>(Wih1, Whh1, bih1, bhh1, wf1, b1v, wid, l15, lhi);
  load_wb<4>(Wih2, Whh2, bih2, bhh2, wf2, b2v, wid, l15, lhi);

  // zero all act tiles (h(-1) = 0 in both slots)
  #pragma unroll
  for (int i = 0; i < 2; ++i){
    *reinterpret_cast<int4*>(act0 + (tid + i*256)*16) = make_int4(0,0,0,0);
    *reinterpret_cast<int4*>(act1 + (tid + i*256)*16) = make_int4(0,0,0,0);
    *reinterpret_cast<int4*>(act2 + (tid + i*256)*16) = make_int4(0,0,0,0);
  }

  // x staging: thread covers (row = tid>>4, float cols (tid&15)*2 .. +1)
  const int xrow = tid >> 4;
  const int xc   = (tid & 15)*2;
  const float* xbase = x + ((size_t)(row0 + xrow)*TSTEPS)*32 + xc;
  {
    float2 v0 = *reinterpret_cast<const float2*>(xbase);        // x(0) -> slot 0
    unsigned pk = (unsigned)f2bf(v0.x) | ((unsigned)f2bf(v0.y) << 16);
    *reinterpret_cast<unsigned*>(act0 + swz(xrow, xc*2)) = pk;
  }
  float2 xr = *reinterpret_cast<const float2*>(xbase + 32);     // x(1) in flight
  __syncthreads();

  float cst0[4] = {0,0,0,0}, cst1[4] = {0,0,0,0}, cst2[4] = {0,0,0,0};
  ushort h0r[4], h1r[4], h2r[4];

  for (int t = 0; t < TSTEPS; ++t){
    const int sl = t & 1;        // slot written this step
    const int rs = sl ^ 1;       // slot holding h(t-1)

    // ---- phase A: everything independent of this step's handoffs ----
    f32x4 a0[4], a1[4], a2[4];
    acc_init(a0, b0v);
    mfma_kt(act0, 32*sl,           wf0[0], a0, l15, lhi);  // x(t)
    mfma_kt(act0, 64 + 64*rs,      wf0[1], a0, l15, lhi);  // h0(t-1)
    mfma_kt(act0, 64 + 64*rs + 32, wf0[2], a0, l15, lhi);
    acc_init(a1, b1v);
    mfma_kt(act1, 64 + 64*rs,      wf1[2], a1, l15, lhi);  // h1(t-1)
    mfma_kt(act1, 64 + 64*rs + 32, wf1[3], a1, l15, lhi);
    acc_init(a2, b2v);
    mfma_kt(act2, 64 + 64*rs,      wf2[2], a2, l15, lhi);  // h2(t-1)
    mfma_kt(act2, 64 + 64*rs + 32, wf2[3], a2, l15, lhi);

    // stage x(t+1) into slot sl^1; prefetch x(t+2) (long slack)
    {
      unsigned pk = (unsigned)f2bf(xr.x) | ((unsigned)f2bf(xr.y) << 16);
      *reinterpret_cast<unsigned*>(act0 + swz(xrow, (32*rs + xc)*2)) = pk;
      int tn = (t + 2 < TSTEPS) ? t + 2 : TSTEPS - 1;
      xr = *reinterpret_cast<const float2*>(xbase + (size_t)tn*32);
    }

    ew(a0, cst0, h0r);
    write_h(act0, 64 + 64*sl, h0r, wid, l15, lhi);   // h0 state
    write_h(act1, 0,          h0r, wid, l15, lhi);   // layer1 input
    __syncthreads();                                 // B1

    // ---- phase B: layer1 input-half ----
    mfma_kt(act1,  0, wf1[0], a1, l15, lhi);
    mfma_kt(act1, 32, wf1[1], a1, l15, lhi);
    ew(a1, cst1, h1r);
    write_h(act1, 64 + 64*sl, h1r, wid, l15, lhi);   // h1 state
    write_h(act2, 0,          h1r, wid, l15, lhi);   // layer2 input
    __syncthreads();                                 // B2

    // ---- phase C: layer2 input-half ----
    mfma_kt(act2,  0, wf2[0], a2, l15, lhi);
    mfma_kt(act2, 32, wf2[1], a2, l15, lhi);
    ew(a2, cst2, h2r);
    write_h(act2, 64 + 64*sl, h2r, wid, l15, lhi);   // h2 state
    __syncthreads();                                 // B3
  }

  // ---- fused FC head: final h2 lives in act2 slot (TSTEPS-1)&1 = 1 ----
  {
    const int row  = tid & 15;
    const int slot = tid >> 4;
    float hv[HID];
    #pragma unroll
    for (int i = 0; i < HID; ++i)
      hv[i] = bf2f(*reinterpret_cast<const ushort*>(act2 + swz(row, (128 + i)*2)));
    float p = 0.f;
    #pragma unroll
    for (int jj = 0; jj < 2; ++jj){
      int j = slot*2 + jj;
      float z = fc1b[j];
      #pragma unroll
      for (int i = 0; i < HID; ++i) z += hv[i]*fc1w[j*HID + i];
      z = fmaxf(z, 0.f);
      p += z * fc2w[j];
    }
    fcbuf[row*16 + slot] = p;
  }
  __syncthreads();
  if (tid < BT){
    float s = fc2b[0];
    #pragma unroll
    for (int k = 0; k < 16; ++k) s += fcbuf[tid*16 + k];
    out[row0 + tid] = s;
  }
}

extern "C" void kernel_launch(void* const* d_in, const int* in_sizes, int n_in,
                              void* d_out, int out_size, void* d_ws, size_t ws_size,
                              hipStream_t stream){
  const float* x    = (const float*)d_in[0];
  const float* Wih0 = (const float*)d_in[1];
  const float* Whh0 = (const float*)d_in[2];
  const float* bih0 = (const float*)d_in[3];
  const float* bhh0 = (const float*)d_in[4];
  const float* Wih1 = (const float*)d_in[5];
  const float* Whh1 = (const float*)d_in[6];
  const float* bih1 = (const float*)d_in[7];
  const float* bhh1 = (const float*)d_in[8];
  const float* Wih2 = (const float*)d_in[9];
  const float* Whh2 = (const float*)d_in[10];
  const float* bih2 = (const float*)d_in[11];
  const float* bhh2 = (const float*)d_in[12];
  const float* fc1w = (const float*)d_in[13];
  const float* fc1b = (const float*)d_in[14];
  const float* fc2w = (const float*)d_in[15];
  const float* fc2b = (const float*)d_in[16];

  lstm3_fused_kernel<<<BATCH/BT, 256, 0, stream>>>(x,
      Wih0, Whh0, bih0, bhh0,
      Wih1, Whh1, bih1, bhh1,
      Wih2, Whh2, bih2, bhh2,
      fc1w, fc1b, fc2w, fc2b, (float*)d_out);
}

// Round 4
// 314.906 us; speedup vs baseline: 2.2737x; 1.3373x over previous
//
#include <hip/hip_runtime.h>

typedef __attribute__((ext_vector_type(8))) short bf16x8;
typedef __attribute__((ext_vector_type(4))) float f32x4;

#define HID 64
#define TSTEPS 256
#define BATCH 4096
#define BT 16
#define RST 1024          // bytes per LDS row
// byte-column regions within each 1024-B row (each 128-B aligned, 2 slots x 128 B):
#define XOFF  0           // x: 32 bf16 cols used per slot
#define H0OFF 256
#define H1OFF 512
#define H2OFF 768

__device__ __forceinline__ float frcp(float x){ return __builtin_amdgcn_rcpf(x); }
__device__ __forceinline__ float fexp2(float x){ return __builtin_amdgcn_exp2f(x); }

__device__ __forceinline__ ushort f2bf(float f){
  unsigned u = __float_as_uint(f);
  u += 0x7fff + ((u>>16)&1);
  return (ushort)(u>>16);
}
__device__ __forceinline__ float bf2f(ushort u){ return __uint_as_float(((unsigned)u)<<16); }
__device__ __forceinline__ unsigned cvtpk(float lo, float hi){
  unsigned r;
  asm("v_cvt_pk_bf16_f32 %0, %1, %2" : "=v"(r) : "v"(lo), "v"(hi));
  return r;
}

// Weights pre-scaled by log2(e) (gates i,f,o) / 2*log2(e) (gate g) so the
// elementwise path uses bare v_exp_f32 (2^x) with free negate modifiers.
template<int KS>
__device__ __forceinline__ void load_wb(const float* __restrict__ Wih,
    const float* __restrict__ Whh, const float* __restrict__ bih,
    const float* __restrict__ bhh, bf16x8 (&wf)[KS][4], float (&bv)[4],
    int wid, int l15, int lhi){
  const int IN = KS*32 - 64;   // 32 (layer0) or 64
  const float L2E = 1.4426950408889634f;
  #pragma unroll
  for (int g = 0; g < 4; ++g){
    const float sc = (g == 2) ? 2.f*L2E : L2E;
    int n = g*64 + wid*16 + l15;          // gate column (B col = lane&15)
    bv[g] = (bih[n] + bhh[n]) * sc;
    #pragma unroll
    for (int kt = 0; kt < KS; ++kt){
      int kb = kt*32 + lhi*8;             // same kappa(lane,j) as A-frag reads
      const float* src = (kb < IN) ? (Wih + (size_t)n*IN + kb)
                                   : (Whh + (size_t)n*64 + (kb - IN));
      bf16x8 v;
      #pragma unroll
      for (int j = 0; j < 8; ++j) v[j] = (short)f2bf(src[j] * sc);
      wf[kt][g] = v;
    }
  }
}

// Merged-denominator LSTM cell: 5 exp2 + 2 rcp per cell (pre-scaled gates).
__device__ __forceinline__ void ew_pack(const f32x4 (&A)[4], float (&cst)[4],
                                        unsigned &p01, unsigned &p23){
  float h[4];
  #pragma unroll
  for (int r = 0; r < 4; ++r){
    float Ai = fexp2(-A[0][r]);           // e^{-i}
    float Bf = fexp2(-A[1][r]);           // e^{-f}
    float G  = fexp2( A[2][r]);           // e^{2g}
    float O  = fexp2(-A[3][r]);           // e^{-o}
    float a1 = 1.f + Ai, b1 = 1.f + Bf, gp = G + 1.f, gm = G - 1.f;
    float cp = (cst[r]*a1*gp + b1*gm) * frcp(a1*b1*gp);
    cst[r] = cp;
    float C2 = fexp2(cp * 2.8853900817779268f);   // e^{2c'}
    h[r] = (C2 - 1.f) * frcp((1.f + O)*(C2 + 1.f));
  }
  p01 = cvtpk(h[0], h[1]);
  p23 = cvtpk(h[2], h[3]);
}

// One diagonal: layer0@t=d, layer1@t=d-1, layer2@t=d-2 — all independent,
// reading only previous-diagonal LDS slots. ONE barrier per diagonal.
template<int SL, bool L0, bool L1, bool L2>
__device__ __forceinline__ void diag_step(char* lds, int d,
    const bf16x8 (&wf0)[3][4], const bf16x8 (&wf1)[4][4], const bf16x8 (&wf2)[4][4],
    const float (&bv0)[4], const float (&bv1)[4], const float (&bv2)[4],
    float (&cst0)[4], float (&cst1)[4], float (&cst2)[4],
    float2 &xr, const float* __restrict__ xbase,
    int rdA, int rdB, const int (&wA)[4], int xwAddr){
  const int RSo = (SL^1)*128;   // previous-diagonal slot (h reads, x stage)
  const int SLo = SL*128;       // current slot (h writes, x read)

  bf16x8 ax, h0a, h0b, h1a, h1b, h2a, h2b;
  if (L0)       ax  = *reinterpret_cast<const bf16x8*>(lds + rdA + XOFF  + SLo);
  if (L0 || L1){ h0a = *reinterpret_cast<const bf16x8*>(lds + rdA + H0OFF + RSo);
                 h0b = *reinterpret_cast<const bf16x8*>(lds + rdB + H0OFF + RSo); }
  if (L1 || L2){ h1a = *reinterpret_cast<const bf16x8*>(lds + rdA + H1OFF + RSo);
                 h1b = *reinterpret_cast<const bf16x8*>(lds + rdB + H1OFF + RSo); }
  if (L2)      { h2a = *reinterpret_cast<const bf16x8*>(lds + rdA + H2OFF + RSo);
                 h2b = *reinterpret_cast<const bf16x8*>(lds + rdB + H2OFF + RSo); }

  f32x4 A0[4], A1[4], A2[4];
  if (L0){
    #pragma unroll
    for (int g = 0; g < 4; ++g){
      f32x4 c = {bv0[g], bv0[g], bv0[g], bv0[g]};
      c = __builtin_amdgcn_mfma_f32_16x16x32_bf16(ax,  wf0[0][g], c, 0, 0, 0);
      c = __builtin_amdgcn_mfma_f32_16x16x32_bf16(h0a, wf0[1][g], c, 0, 0, 0);
      A0[g] = __builtin_amdgcn_mfma_f32_16x16x32_bf16(h0b, wf0[2][g], c, 0, 0, 0);
    }
  }
  if (L1){
    #pragma unroll
    for (int g = 0; g < 4; ++g){
      f32x4 c = {bv1[g], bv1[g], bv1[g], bv1[g]};
      c = __builtin_amdgcn_mfma_f32_16x16x32_bf16(h0a, wf1[0][g], c, 0, 0, 0);
      c = __builtin_amdgcn_mfma_f32_16x16x32_bf16(h0b, wf1[1][g], c, 0, 0, 0);
      c = __builtin_amdgcn_mfma_f32_16x16x32_bf16(h1a, wf1[2][g], c, 0, 0, 0);
      A1[g] = __builtin_amdgcn_mfma_f32_16x16x32_bf16(h1b, wf1[3][g], c, 0, 0, 0);
    }
  }
  if (L2){
    #pragma unroll
    for (int g = 0; g < 4; ++g){
      f32x4 c = {bv2[g], bv2[g], bv2[g], bv2[g]};
      c = __builtin_amdgcn_mfma_f32_16x16x32_bf16(h1a, wf2[0][g], c, 0, 0, 0);
      c = __builtin_amdgcn_mfma_f32_16x16x32_bf16(h1b, wf2[1][g], c, 0, 0, 0);
      c = __builtin_amdgcn_mfma_f32_16x16x32_bf16(h2a, wf2[2][g], c, 0, 0, 0);
      A2[g] = __builtin_amdgcn_mfma_f32_16x16x32_bf16(h2b, wf2[3][g], c, 0, 0, 0);
    }
  }

  if (L0){   // stage x(d+1) into prev slot; prefetch x(d+2)
    unsigned pk = cvtpk(xr.x, xr.y);
    *reinterpret_cast<unsigned*>(lds + xwAddr + XOFF + RSo) = pk;
    int tn = d + 2; if (tn > TSTEPS-1) tn = TSTEPS-1;
    xr = *reinterpret_cast<const float2*>(xbase + (size_t)tn*32);
  }

  if (L0){
    unsigned p01, p23;
    ew_pack(A0, cst0, p01, p23);
    *reinterpret_cast<ushort*>(lds + wA[0] + H0OFF + SLo) = (ushort)p01;
    *reinterpret_cast<ushort*>(lds + wA[1] + H0OFF + SLo) = (ushort)(p01 >> 16);
    *reinterpret_cast<ushort*>(lds + wA[2] + H0OFF + SLo) = (ushort)p23;
    *reinterpret_cast<ushort*>(lds + wA[3] + H0OFF + SLo) = (ushort)(p23 >> 16);
  }
  if (L1){
    unsigned p01, p23;
    ew_pack(A1, cst1, p01, p23);
    *reinterpret_cast<ushort*>(lds + wA[0] + H1OFF + SLo) = (ushort)p01;
    *reinterpret_cast<ushort*>(lds + wA[1] + H1OFF + SLo) = (ushort)(p01 >> 16);
    *reinterpret_cast<ushort*>(lds + wA[2] + H1OFF + SLo) = (ushort)p23;
    *reinterpret_cast<ushort*>(lds + wA[3] + H1OFF + SLo) = (ushort)(p23 >> 16);
  }
  if (L2){
    unsigned p01, p23;
    ew_pack(A2, cst2, p01, p23);
    *reinterpret_cast<ushort*>(lds + wA[0] + H2OFF + SLo) = (ushort)p01;
    *reinterpret_cast<ushort*>(lds + wA[1] + H2OFF + SLo) = (ushort)(p01 >> 16);
    *reinterpret_cast<ushort*>(lds + wA[2] + H2OFF + SLo) = (ushort)p23;
    *reinterpret_cast<ushort*>(lds + wA[3] + H2OFF + SLo) = (ushort)(p23 >> 16);
  }
  __syncthreads();
}

__global__ __launch_bounds__(256, 1) void lstm3_wave_kernel(
    const float* __restrict__ x,
    const float* Wih0, const float* Whh0, const float* bih0, const float* bhh0,
    const float* Wih1, const float* Whh1, const float* bih1, const float* bhh1,
    const float* Wih2, const float* Whh2, const float* bih2, const float* bhh2,
    const float* __restrict__ fc1w, const float* __restrict__ fc1b,
    const float* __restrict__ fc2w, const float* __restrict__ fc2b,
    float* __restrict__ out){
  __shared__ char lds[BT*RST];
  __shared__ float fcbuf[BT*16];

  const int tid  = threadIdx.x;
  const int lane = tid & 63;
  const int wid  = tid >> 6;
  const int l15  = lane & 15;
  const int lhi  = lane >> 4;
  const int row0 = blockIdx.x * BT;

  bf16x8 wf0[3][4], wf1[4][4], wf2[4][4];
  float bv0[4], bv1[4], bv2[4];
  load_wb<3>(Wih0, Whh0, bih0, bhh0, wf0, bv0, wid, l15, lhi);
  load_wb<4>(Wih1, Whh1, bih1, bhh1, wf1, bv1, wid, l15, lhi);
  load_wb<4>(Wih2, Whh2, bih2, bhh2, wf2, bv2, wid, l15, lhi);

  // Precomputed swizzled LDS addresses (XOR swizzle: byte ^= (row&7)<<4,
  // stays within each 128-B region; slots/regions are +imm offsets).
  const int rdA = l15*RST + ((lhi*16) ^ ((l15 & 7) << 4)); // A-frag, k-tile 0
  const int rdB = rdA ^ 64;                                 // A-frag, k-tile 1
  int wA[4];
  #pragma unroll
  for (int r = 0; r < 4; ++r){
    int row = lhi*4 + r;                                    // C/D row = batch row
    wA[r] = row*RST + (((wid*16 + l15)*2) ^ ((row & 7) << 4));
  }
  const int xrow = tid >> 4;
  const int xwAddr = xrow*RST + (((tid & 15)*4) ^ ((xrow & 7) << 4));
  const float* xbase = x + ((size_t)(row0 + xrow)*TSTEPS)*32 + (tid & 15)*2;

  // zero all LDS (h(-1)=0 both slots), then stage x(0) into slot 0
  #pragma unroll
  for (int i = 0; i < 4; ++i)
    *reinterpret_cast<int4*>(lds + (tid + i*256)*16) = make_int4(0, 0, 0, 0);
  __syncthreads();
  {
    float2 v0 = *reinterpret_cast<const float2*>(xbase);
    *reinterpret_cast<unsigned*>(lds + xwAddr + XOFF) = cvtpk(v0.x, v0.y);
  }
  float2 xr = *reinterpret_cast<const float2*>(xbase + 32);  // x(1)
  __syncthreads();

  float cst0[4] = {0,0,0,0}, cst1[4] = {0,0,0,0}, cst2[4] = {0,0,0,0};

  #define ARGS lds, d, wf0, wf1, wf2, bv0, bv1, bv2, cst0, cst1, cst2, \
               xr, xbase, rdA, rdB, wA, xwAddr
  { int d = 0; diag_step<0, true, false, false>(ARGS); }
  { int d = 1; diag_step<1, true, true,  false>(ARGS); }
  for (int d = 2; d < 256; d += 2){
    diag_step<0, true, true, true>(ARGS);
    ++d;
    diag_step<1, true, true, true>(ARGS);
    --d;
  }
  { int d = 256; diag_step<0, false, true,  true>(ARGS); }
  { int d = 257; diag_step<1, false, false, true>(ARGS); }
  #undef ARGS

  // ---- fused FC head: final h2(255) is in H2 slot 1 (diag 257, SL=1) ----
  {
    const int row  = tid & 15;
    const int slot = tid >> 4;
    const int rx   = (row & 7) << 4;
    float hv[HID];
    #pragma unroll
    for (int i = 0; i < HID; ++i)
      hv[i] = bf2f(*reinterpret_cast<const ushort*>(
                   lds + row*RST + (H2OFF + 128) + ((i*2) ^ rx)));
    float p = 0.f;
    #pragma unroll
    for (int jj = 0; jj < 2; ++jj){
      int j = slot*2 + jj;
      float z = fc1b[j];
      #pragma unroll
      for (int i = 0; i < HID; ++i) z += hv[i]*fc1w[j*HID + i];
      z = fmaxf(z, 0.f);
      p += z * fc2w[j];
    }
    fcbuf[row*16 + slot] = p;
  }
  __syncthreads();
  if (tid < BT){
    float s = fc2b[0];
    #pragma unroll
    for (int k = 0; k < 16; ++k) s += fcbuf[tid*16 + k];
    out[row0 + tid] = s;
  }
}

extern "C" void kernel_launch(void* const* d_in, const int* in_sizes, int n_in,
                              void* d_out, int out_size, void* d_ws, size_t ws_size,
                              hipStream_t stream){
  const float* x    = (const float*)d_in[0];
  const float* Wih0 = (const float*)d_in[1];
  const float* Whh0 = (const float*)d_in[2];
  const float* bih0 = (const float*)d_in[3];
  const float* bhh0 = (const float*)d_in[4];
  const float* Wih1 = (const float*)d_in[5];
  const float* Whh1 = (const float*)d_in[6];
  const float* bih1 = (const float*)d_in[7];
  const float* bhh1 = (const float*)d_in[8];
  const float* Wih2 = (const float*)d_in[9];
  const float* Whh2 = (const float*)d_in[10];
  const float* bih2 = (const float*)d_in[11];
  const float* bhh2 = (const float*)d_in[12];
  const float* fc1w = (const float*)d_in[13];
  const float* fc1b = (const float*)d_in[14];
  const float* fc2w = (const float*)d_in[15];
  const float* fc2b = (const float*)d_in[16];

  lstm3_wave_kernel<<<BATCH/BT, 256, 0, stream>>>(x,
      Wih0, Whh0, bih0, bhh0,
      Wih1, Whh1, bih1, bhh1,
      Wih2, Whh2, bih2, bhh2,
      fc1w, fc1b, fc2w, fc2b, (float*)d_out);
}